// Round 9
// baseline (849.616 us; speedup 1.0000x reference)
//
#include <hip/hip_runtime.h>
#include <hip/hip_bf16.h>

#define NPIX   65536
#define TT     5
#define CC     10
#define HH     32
#define WIDTH  64
#define KW     32
#define OUTC   10

// ---- workspace layout (float offsets) ----
// LSTM weights group-major/k-major gate-packed: [grp][k][j8][g], rows of 32 floats
#define OFF_L0I    0        // 1280  [grp][c][j8][g]
#define OFF_L0H    1280     // 4096  [grp][k][j8][g]
#define OFF_L1I    5376     // 4096
#define OFF_L1H    9472     // 4096
#define OFF_B0     13568    // 128   [j][g]
#define OFF_B1     13696    // 128
#define OFF_FC1W   13824    // 2048  [k][ch]
#define OFF_FC1B   15872    // 64
#define OFF_CWT    16384    // 16384 [k][co][ci]  (plain transpose, SGPR-streamed)
#define OFF_CB     32768    // 256
#define OFF_FC2W   33024    // 2048  [m][ch] (row-major, as-is)
#define OFF_FC2B   35072    // 32
#define OFF_FC3T   35104    // 320   [m][oc]
#define OFF_FC3B   35424    // 16
#define OFF_GW     35440    // 8
#define OFF_FEATS_A 36864
#define OFF_FEATS_B (36864 + 8388608)

#define STRAIGHT_ATTR_IDX (65025 * 3)

__device__ __forceinline__ float sigf(float x)  { return 1.0f / (1.0f + __expf(-x)); }
__device__ __forceinline__ float tanhf_(float x){ return 1.0f - 2.0f / (__expf(2.0f * x) + 1.0f); }

// ---------------- prep: pack params ----------------
__global__ __launch_bounds__(256, 1)
void prep_kernel(const float* Wih0, const float* Whh0,
                 const float* bih0, const float* bhh0,
                 const float* Wih1, const float* Whh1,
                 const float* bih1, const float* bhh1,
                 const float* fc1w, const float* fc1b,
                 const float* convw, const float* convb,
                 const float* fc2w, const float* fc2b,
                 const float* fc3w, const float* fc3b,
                 const float* gparam, const float* eattr,
                 float* P) {
    int tid = blockIdx.x * blockDim.x + threadIdx.x;
    int stride = gridDim.x * blockDim.x;
    // L0I [grp][c][j8][g]: idx = ((grp*10+c)*8+j8)*4+g
    for (int idx = tid; idx < 1280; idx += stride) {
        int g = idx & 3, j8 = (idx >> 2) & 7, rest = idx >> 5;
        int c = rest % 10, grp = rest / 10;
        P[OFF_L0I + idx] = Wih0[(g * 32 + grp * 8 + j8) * 10 + c];
    }
    // H-type [grp][k][j8][g]: idx = ((grp*32+k)*8+j8)*4+g
    for (int idx = tid; idx < 4096; idx += stride) {
        int g = idx & 3, j8 = (idx >> 2) & 7, rest = idx >> 5;
        int k = rest & 31, grp = rest >> 5;
        int row = (g * 32 + grp * 8 + j8) * 32 + k;
        P[OFF_L0H + idx] = Whh0[row];
        P[OFF_L1I + idx] = Wih1[row];
        P[OFF_L1H + idx] = Whh1[row];
    }
    for (int idx = tid; idx < 128; idx += stride) {
        int g = idx & 3, j = idx >> 2;
        P[OFF_B0 + idx] = bih0[g * 32 + j] + bhh0[g * 32 + j];
        P[OFF_B1 + idx] = bih1[g * 32 + j] + bhh1[g * 32 + j];
    }
    // fc1 k-major [k][ch]
    for (int idx = tid; idx < 2048; idx += stride) {
        int ch = idx & 63, k = idx >> 6;
        P[OFF_FC1W + idx] = fc1w[ch * 32 + k];
    }
    for (int i = tid; i < 64; i += stride) P[OFF_FC1B + i] = fc1b[i];
    // conv [k][co][ci] <- convw[k][ci][co]
    for (int idx = tid; idx < 16384; idx += stride) {
        int k = idx >> 12, r = idx & 4095, co = r >> 6, ci = r & 63;
        P[OFF_CWT + idx] = convw[k * 4096 + ci * 64 + co];
    }
    for (int i = tid; i < 256; i += stride) P[OFF_CB + i] = convb[i];
    for (int i = tid; i < 2048; i += stride) P[OFF_FC2W + i] = fc2w[i];   // [m][ch] as-is
    for (int i = tid; i < 32;  i += stride) P[OFF_FC2B + i] = fc2b[i];
    // fc3 transposed [m][oc]
    for (int idx = tid; idx < 320; idx += stride) {
        int m = idx / 10, oc = idx % 10;
        P[OFF_FC3T + idx] = fc3w[oc * 32 + m];
    }
    for (int i = tid; i < 10; i += stride) P[OFF_FC3B + i] = fc3b[i];
    for (int idx = tid; idx < 8; idx += stride) {
        int k = idx >> 1;
        float g = gparam[k];
        float denom = g * g + 1e-8f;
        float a = (idx & 1) ? eattr[0] : eattr[STRAIGHT_ATTR_IDX];
        P[OFF_GW + idx] = __expf(-(a * a) / denom);
    }
}

// ---------------- LSTM: 128 thr, 1 px/lane, 4 unrolled unit-groups of 8 ----------------
// z[8] (32 VGPRs) per group avoids R8's z[32]=128-VGPR pressure (VGPR_Count was 112 -> spill).
// Weights: uniform scalar stream, 32-float rows per k (2x s_load_dwordx16).
// h state: per-lane LDS columns (own column only -> no barriers).
__global__ __launch_bounds__(128, 1)
void lstm_fc1_kernel(const float* __restrict__ x,
                     const float* __restrict__ P,
                     float* __restrict__ feats) {
    __shared__ float XS[CC * 128];   // 5120 B
    __shared__ float H0[HH * 128];   // 16384 B
    __shared__ float H1[HH * 128];   // 16384 B  (37888 total)

    int tid = threadIdx.x;
    int n = blockIdx.x * 128 + tid;
    int b = n >> 16;
    int pix = n & (NPIX - 1);
    const float* xb = x + (size_t)b * TT * CC * NPIX + pix;

    float c0[HH], c1[HH], hn[HH];
#pragma unroll
    for (int jj = 0; jj < HH; jj++) {
        c0[jj] = 0.f; c1[jj] = 0.f;
        H0[jj * 128 + tid] = 0.f;
        H1[jj * 128 + tid] = 0.f;
    }

#pragma unroll 1
    for (int t = 0; t < TT; t++) {
#pragma unroll
        for (int c = 0; c < CC; c++)
            XS[c * 128 + tid] = xb[(size_t)(t * CC + c) * NPIX];

        // ---- layer 0 ----
#pragma unroll
        for (int grp = 0; grp < 4; grp++) {
            float4 z[8];
#pragma unroll
            for (int j8 = 0; j8 < 8; j8++)
                z[j8] = *(const float4*)(P + OFF_B0 + (grp * 8 + j8) * 4);
#pragma unroll 1
            for (int c = 0; c < CC; c++) {
                float xv = XS[c * 128 + tid];
                const float* wr = P + OFF_L0I + (grp * 10 + c) * 32;
#pragma unroll
                for (int j8 = 0; j8 < 8; j8++) {
                    z[j8].x = __builtin_fmaf(wr[j8 * 4 + 0], xv, z[j8].x);
                    z[j8].y = __builtin_fmaf(wr[j8 * 4 + 1], xv, z[j8].y);
                    z[j8].z = __builtin_fmaf(wr[j8 * 4 + 2], xv, z[j8].z);
                    z[j8].w = __builtin_fmaf(wr[j8 * 4 + 3], xv, z[j8].w);
                }
            }
#pragma unroll 1
            for (int k = 0; k < HH; k++) {
                float hv = H0[k * 128 + tid];
                const float* wr = P + OFF_L0H + (grp * 32 + k) * 32;
#pragma unroll
                for (int j8 = 0; j8 < 8; j8++) {
                    z[j8].x = __builtin_fmaf(wr[j8 * 4 + 0], hv, z[j8].x);
                    z[j8].y = __builtin_fmaf(wr[j8 * 4 + 1], hv, z[j8].y);
                    z[j8].z = __builtin_fmaf(wr[j8 * 4 + 2], hv, z[j8].z);
                    z[j8].w = __builtin_fmaf(wr[j8 * 4 + 3], hv, z[j8].w);
                }
            }
#pragma unroll
            for (int j8 = 0; j8 < 8; j8++) {
                int j = grp * 8 + j8;
                float cn = sigf(z[j8].y) * c0[j] + sigf(z[j8].x) * tanhf_(z[j8].z);
                c0[j] = cn;
                hn[j] = sigf(z[j8].w) * tanhf_(cn);
            }
        }
#pragma unroll
        for (int jj = 0; jj < HH; jj++) H0[jj * 128 + tid] = hn[jj];

        // ---- layer 1 ----
#pragma unroll
        for (int grp = 0; grp < 4; grp++) {
            float4 z[8];
#pragma unroll
            for (int j8 = 0; j8 < 8; j8++)
                z[j8] = *(const float4*)(P + OFF_B1 + (grp * 8 + j8) * 4);
#pragma unroll 1
            for (int k = 0; k < HH; k++) {
                float hv = H0[k * 128 + tid];
                const float* wr = P + OFF_L1I + (grp * 32 + k) * 32;
#pragma unroll
                for (int j8 = 0; j8 < 8; j8++) {
                    z[j8].x = __builtin_fmaf(wr[j8 * 4 + 0], hv, z[j8].x);
                    z[j8].y = __builtin_fmaf(wr[j8 * 4 + 1], hv, z[j8].y);
                    z[j8].z = __builtin_fmaf(wr[j8 * 4 + 2], hv, z[j8].z);
                    z[j8].w = __builtin_fmaf(wr[j8 * 4 + 3], hv, z[j8].w);
                }
            }
#pragma unroll 1
            for (int k = 0; k < HH; k++) {
                float hv = H1[k * 128 + tid];
                const float* wr = P + OFF_L1H + (grp * 32 + k) * 32;
#pragma unroll
                for (int j8 = 0; j8 < 8; j8++) {
                    z[j8].x = __builtin_fmaf(wr[j8 * 4 + 0], hv, z[j8].x);
                    z[j8].y = __builtin_fmaf(wr[j8 * 4 + 1], hv, z[j8].y);
                    z[j8].z = __builtin_fmaf(wr[j8 * 4 + 2], hv, z[j8].z);
                    z[j8].w = __builtin_fmaf(wr[j8 * 4 + 3], hv, z[j8].w);
                }
            }
#pragma unroll
            for (int j8 = 0; j8 < 8; j8++) {
                int j = grp * 8 + j8;
                float cn = sigf(z[j8].y) * c1[j] + sigf(z[j8].x) * tanhf_(z[j8].z);
                c1[j] = cn;
                hn[j] = sigf(z[j8].w) * tanhf_(cn);
            }
        }
#pragma unroll
        for (int jj = 0; jj < HH; jj++) H1[jj * 128 + tid] = hn[jj];
    }

    // ---- fc1 + relu (k-major scalar weights) ----
    float f[WIDTH];
#pragma unroll
    for (int ch = 0; ch < WIDTH; ch++) f[ch] = P[OFF_FC1B + ch];
#pragma unroll 1
    for (int k = 0; k < HH; k++) {
        float hv = H1[k * 128 + tid];
        const float* wr = P + OFF_FC1W + k * 64;
#pragma unroll
        for (int ch = 0; ch < WIDTH; ch++)
            f[ch] = __builtin_fmaf(wr[ch], hv, f[ch]);
    }
    float* fb = feats + (size_t)b * WIDTH * NPIX + pix;
#pragma unroll
    for (int ch = 0; ch < WIDTH; ch++)
        fb[(size_t)ch * NPIX] = fmaxf(f[ch], 0.f);
}

// ---------------- conv layer: stencil + 64x64 matmul, SGPR weights, no LDS ----------------
__global__ __launch_bounds__(256, 1)
void conv_mm_kernel(const float* __restrict__ Fin, float* __restrict__ Fout,
                    const float* __restrict__ P, int k, int dorelu) {
    int n = blockIdx.x * 256 + threadIdx.x;
    int b = n >> 16;
    int pix = n & (NPIX - 1);
    int i = pix >> 8, j = pix & 255;
    float wstr = P[OFF_GW + 2 * k], wdiag = P[OFF_GW + 2 * k + 1];
    float fu = (i > 0) ? wstr : 0.f, fd = (i < 255) ? wstr : 0.f;
    float fl = (j > 0) ? wstr : 0.f, fr = (j < 255) ? wstr : 0.f;
    float ful = (i > 0 && j > 0) ? wdiag : 0.f, fur = (i > 0 && j < 255) ? wdiag : 0.f;
    float fdl = (i < 255 && j > 0) ? wdiag : 0.f, fdr = (i < 255 && j < 255) ? wdiag : 0.f;

    const float* fb = Fin + (size_t)b * WIDTH * NPIX + pix;
    float u[WIDTH];
#pragma unroll
    for (int ch = 0; ch < WIDTH; ch++) {
        const float* yc = fb + (size_t)ch * NPIX;
        float v = yc[0];
        v += fu * yc[-256] + fd * yc[256] + fl * yc[-1] + fr * yc[1];
        v += ful * yc[-257] + fur * yc[-255] + fdl * yc[255] + fdr * yc[257];
        u[ch] = v;
    }

    const float* wbase = P + OFF_CWT + (k << 12);
    const float* cb = P + OFF_CB + k * 64;
    float* ob = Fout + (size_t)b * WIDTH * NPIX + pix;
#pragma unroll 1
    for (int co = 0; co < 64; co++) {
        const float* wr = wbase + co * 64;
        float acc = cb[co];
#pragma unroll
        for (int ci = 0; ci < WIDTH; ci++)
            acc = __builtin_fmaf(wr[ci], u[ci], acc);
        ob[(size_t)co * NPIX] = dorelu ? fmaxf(acc, 0.f) : acc;
    }
}

// ---------------- head: f -> relu(fc2) -> fc3, SGPR weights, no LDS ----------------
__global__ __launch_bounds__(256, 1)
void head_kernel(const float* __restrict__ Fin, const float* __restrict__ P,
                 float* __restrict__ out) {
    int n = blockIdx.x * 256 + threadIdx.x;
    int b = n >> 16;
    int pix = n & (NPIX - 1);
    const float* fb = Fin + (size_t)b * WIDTH * NPIX + pix;
    float f[WIDTH];
#pragma unroll
    for (int ch = 0; ch < WIDTH; ch++) f[ch] = fb[(size_t)ch * NPIX];

    float oo[OUTC];
#pragma unroll
    for (int oc = 0; oc < OUTC; oc++) oo[oc] = P[OFF_FC3B + oc];
#pragma unroll 1
    for (int m = 0; m < KW; m++) {
        const float* wr = P + OFF_FC2W + m * 64;
        float a = P[OFF_FC2B + m];
#pragma unroll
        for (int ch = 0; ch < WIDTH; ch++)
            a = __builtin_fmaf(wr[ch], f[ch], a);
        a = fmaxf(a, 0.f);
        const float* w3 = P + OFF_FC3T + m * 10;
#pragma unroll
        for (int oc = 0; oc < OUTC; oc++)
            oo[oc] = __builtin_fmaf(w3[oc], a, oo[oc]);
    }
    float* ob = out + (size_t)b * OUTC * NPIX + pix;
#pragma unroll
    for (int oc = 0; oc < OUTC; oc++) ob[(size_t)oc * NPIX] = oo[oc];
}

extern "C" void kernel_launch(void* const* d_in, const int* in_sizes, int n_in,
                              void* d_out, int out_size, void* d_ws, size_t ws_size,
                              hipStream_t stream) {
    const float* x     = (const float*)d_in[0];
    const float* eattr = (const float*)d_in[3];
    const float* Wih0  = (const float*)d_in[4];
    const float* Whh0  = (const float*)d_in[5];
    const float* bih0  = (const float*)d_in[6];
    const float* bhh0  = (const float*)d_in[7];
    const float* Wih1  = (const float*)d_in[8];
    const float* Whh1  = (const float*)d_in[9];
    const float* bih1  = (const float*)d_in[10];
    const float* bhh1  = (const float*)d_in[11];
    const float* fc1w  = (const float*)d_in[12];
    const float* fc1b  = (const float*)d_in[13];
    const float* convw = (const float*)d_in[14];
    const float* convb = (const float*)d_in[15];
    const float* gparam= (const float*)d_in[16];
    const float* fc2w  = (const float*)d_in[17];
    const float* fc2b  = (const float*)d_in[18];
    const float* fc3w  = (const float*)d_in[19];
    const float* fc3b  = (const float*)d_in[20];

    float* P  = (float*)d_ws;
    float* FA = P + OFF_FEATS_A;
    float* FB = P + OFF_FEATS_B;

    prep_kernel<<<64, 256, 0, stream>>>(Wih0, Whh0, bih0, bhh0, Wih1, Whh1, bih1, bhh1,
                                        fc1w, fc1b, convw, convb, fc2w, fc2b, fc3w, fc3b,
                                        gparam, eattr, P);
    lstm_fc1_kernel<<<1024, 128, 0, stream>>>(x, P, FA);
    conv_mm_kernel<<<512, 256, 0, stream>>>(FA, FB, P, 0, 1);
    conv_mm_kernel<<<512, 256, 0, stream>>>(FB, FA, P, 1, 1);
    conv_mm_kernel<<<512, 256, 0, stream>>>(FA, FB, P, 2, 1);
    conv_mm_kernel<<<512, 256, 0, stream>>>(FB, FA, P, 3, 0);
    head_kernel<<<512, 256, 0, stream>>>(FA, P, (float*)d_out);
}